// Round 1
// baseline (1402.982 us; speedup 1.0000x reference)
//
#include <hip/hip_runtime.h>

#define DF 256  // feature dim (verified from in_sizes at launch)

// ---- accumulate: 4 nodes per 256-thread block, 64 lanes per node row ----
__global__ void cp_accum(const float* __restrict__ x, const float* __restrict__ h,
                         const int* __restrict__ cmap,
                         float* __restrict__ xp, float* __restrict__ hp,
                         float* __restrict__ counts, int n_nodes) {
    int node = blockIdx.x * 4 + (threadIdx.x >> 6);
    if (node >= n_nodes) return;
    int lane = threadIdx.x & 63;
    int c = cmap[node];

    const float4* x4 = reinterpret_cast<const float4*>(x + (size_t)node * DF);
    const float4* h4 = reinterpret_cast<const float4*>(h + (size_t)node * DF);
    float4 xv = x4[lane];
    float4 hv = h4[lane];

    float* xo = xp + (size_t)c * DF + lane * 4;
    float* ho = hp + (size_t)c * DF + lane * 4;
    atomicAdd(xo + 0, xv.x);
    atomicAdd(xo + 1, xv.y);
    atomicAdd(xo + 2, xv.z);
    atomicAdd(xo + 3, xv.w);
    atomicAdd(ho + 0, hv.x);
    atomicAdd(ho + 1, hv.y);
    atomicAdd(ho + 2, hv.z);
    atomicAdd(ho + 3, hv.w);
    if (lane == 0) atomicAdd(&counts[c], 1.0f);
}

// ---- finalize: divide sums by max(count,1), float4 granularity ----
__global__ void cp_finalize(float* __restrict__ xp, float* __restrict__ hp,
                            const float* __restrict__ counts, int C) {
    int idx = blockIdx.x * blockDim.x + threadIdx.x;   // one float4 per thread
    int total = C * (DF / 4);
    if (idx >= total) return;
    int c = idx >> 6;   // DF/4 == 64 float4 per row
    float inv = 1.0f / fmaxf(counts[c], 1.0f);
    float4* x4 = reinterpret_cast<float4*>(xp);
    float4* h4 = reinterpret_cast<float4*>(hp);
    float4 v = x4[idx];
    v.x *= inv; v.y *= inv; v.z *= inv; v.w *= inv;
    x4[idx] = v;
    float4 w = h4[idx];
    w.x *= inv; w.y *= inv; w.z *= inv; w.w *= inv;
    h4[idx] = w;
}

// ---- pos gather ----
__global__ void cp_pos(const float* __restrict__ pos, const int* __restrict__ sidx,
                       float* __restrict__ out, int C) {
    int i = blockIdx.x * blockDim.x + threadIdx.x;
    if (i >= C) return;
    int s = sidx[i];
    out[(size_t)i * 3 + 0] = pos[(size_t)s * 3 + 0];
    out[(size_t)i * 3 + 1] = pos[(size_t)s * 3 + 1];
    out[(size_t)i * 3 + 2] = pos[(size_t)s * 3 + 2];
}

extern "C" void kernel_launch(void* const* d_in, const int* in_sizes, int n_in,
                              void* d_out, int out_size, void* d_ws, size_t ws_size,
                              hipStream_t stream) {
    const float* x    = (const float*)d_in[0];
    const float* h    = (const float*)d_in[1];
    const float* pos  = (const float*)d_in[2];
    const int*   cmap = (const int*)d_in[3];
    const int*   sidx = (const int*)d_in[4];

    const int n_nodes = in_sizes[2] / 3;     // pos is [N,3]
    const int C       = in_sizes[4];         // sample_index is [C]
    // D is DF==256 by construction (in_sizes[0] / n_nodes)

    float* out    = (float*)d_out;
    float* xp     = out;
    float* hp     = out + (size_t)C * DF;
    float* pout   = out + (size_t)2 * C * DF;
    float* counts = (float*)d_ws;            // C floats

    // zero the sum regions + counts every call (d_out/d_ws not re-poisoned)
    hipMemsetAsync(xp, 0, (size_t)2 * C * DF * sizeof(float), stream);
    hipMemsetAsync(counts, 0, (size_t)C * sizeof(float), stream);

    cp_accum<<<(n_nodes + 3) / 4, 256, 0, stream>>>(x, h, cmap, xp, hp, counts, n_nodes);

    int fin_total  = C * (DF / 4);
    cp_finalize<<<(fin_total + 255) / 256, 256, 0, stream>>>(xp, hp, counts, C);

    cp_pos<<<(C + 255) / 256, 256, 0, stream>>>(pos, sidx, pout, C);
}

// Round 2
// 148.457 us; speedup vs baseline: 9.4504x; 9.4504x over previous
//
#include <hip/hip_runtime.h>

#define DF 256  // feature dim

// ---- 1. histogram: counts[c] = #nodes in cluster c ----
__global__ void cp_count(const int* __restrict__ cmap, int* __restrict__ counts, int n) {
    int i = blockIdx.x * blockDim.x + threadIdx.x;
    if (i < n) atomicAdd(&counts[cmap[i]], 1);
}

// ---- 2a. per-block exclusive scan (256 elems/block) ----
__global__ void cp_scanA(const int* __restrict__ counts, int* __restrict__ offsets,
                         int* __restrict__ blocksums, int C) {
    __shared__ int s[256];
    int tid = threadIdx.x;
    int i = blockIdx.x * 256 + tid;
    int v = (i < C) ? counts[i] : 0;
    s[tid] = v;
    __syncthreads();
    for (int off = 1; off < 256; off <<= 1) {
        int t = (tid >= off) ? s[tid - off] : 0;
        __syncthreads();
        s[tid] += t;
        __syncthreads();
    }
    if (i < C) offsets[i] = s[tid] - v;           // exclusive within block
    if (tid == 255) blocksums[blockIdx.x] = s[255];
}

// ---- 2b. scan the block sums (nb <= 256 fast path) ----
__global__ void cp_scanB(int* __restrict__ blocksums, int nb) {
    __shared__ int s[256];
    int tid = threadIdx.x;
    if (nb <= 256) {
        int v = (tid < nb) ? blocksums[tid] : 0;
        s[tid] = v;
        __syncthreads();
        for (int off = 1; off < 256; off <<= 1) {
            int t = (tid >= off) ? s[tid - off] : 0;
            __syncthreads();
            s[tid] += t;
            __syncthreads();
        }
        if (tid < nb) blocksums[tid] = s[tid] - v;
    } else if (tid == 0) {                         // generic fallback
        int run = 0;
        for (int k = 0; k < nb; ++k) { int t = blocksums[k]; blocksums[k] = run; run += t; }
    }
}

// ---- 2c. add block offsets ----
__global__ void cp_scanC(int* __restrict__ offsets, const int* __restrict__ blocksums, int C) {
    int i = blockIdx.x * 256 + threadIdx.x;
    if (i < C) offsets[i] += blocksums[blockIdx.x];
}

// ---- 3. bucket-fill node indices ----
__global__ void cp_fill(const int* __restrict__ cmap, const int* __restrict__ offsets,
                        int* __restrict__ cursor, int* __restrict__ node_list, int n) {
    int i = blockIdx.x * blockDim.x + threadIdx.x;
    if (i < n) {
        int c = cmap[i];
        int slot = atomicAdd(&cursor[c], 1);
        node_list[offsets[c] + slot] = i;
    }
}

// ---- 4. pool: one wave (64 lanes) per cluster, register accumulate ----
__global__ void cp_pool(const float* __restrict__ x, const float* __restrict__ h,
                        const int* __restrict__ offsets, const int* __restrict__ counts,
                        const int* __restrict__ node_list,
                        float* __restrict__ xp, float* __restrict__ hp, int C) {
    int c = blockIdx.x * 4 + (threadIdx.x >> 6);
    if (c >= C) return;
    int lane = threadIdx.x & 63;
    int start = offsets[c];
    int len = counts[c];
    float4 ax = make_float4(0.f, 0.f, 0.f, 0.f);
    float4 ah = make_float4(0.f, 0.f, 0.f, 0.f);
    for (int k = 0; k < len; ++k) {
        int node = node_list[start + k];           // wave-uniform
        const float4* x4 = reinterpret_cast<const float4*>(x + (size_t)node * DF);
        const float4* h4 = reinterpret_cast<const float4*>(h + (size_t)node * DF);
        float4 xv = x4[lane];
        float4 hv = h4[lane];
        ax.x += xv.x; ax.y += xv.y; ax.z += xv.z; ax.w += xv.w;
        ah.x += hv.x; ah.y += hv.y; ah.z += hv.z; ah.w += hv.w;
    }
    float inv = 1.0f / (float)(len > 0 ? len : 1);
    ax.x *= inv; ax.y *= inv; ax.z *= inv; ax.w *= inv;
    ah.x *= inv; ah.y *= inv; ah.z *= inv; ah.w *= inv;
    reinterpret_cast<float4*>(xp + (size_t)c * DF)[lane] = ax;
    reinterpret_cast<float4*>(hp + (size_t)c * DF)[lane] = ah;
}

// ---- 5. pos gather ----
__global__ void cp_pos(const float* __restrict__ pos, const int* __restrict__ sidx,
                       float* __restrict__ out, int C) {
    int i = blockIdx.x * blockDim.x + threadIdx.x;
    if (i >= C) return;
    int s = sidx[i];
    out[(size_t)i * 3 + 0] = pos[(size_t)s * 3 + 0];
    out[(size_t)i * 3 + 1] = pos[(size_t)s * 3 + 1];
    out[(size_t)i * 3 + 2] = pos[(size_t)s * 3 + 2];
}

extern "C" void kernel_launch(void* const* d_in, const int* in_sizes, int n_in,
                              void* d_out, int out_size, void* d_ws, size_t ws_size,
                              hipStream_t stream) {
    const float* x    = (const float*)d_in[0];
    const float* h    = (const float*)d_in[1];
    const float* pos  = (const float*)d_in[2];
    const int*   cmap = (const int*)d_in[3];
    const int*   sidx = (const int*)d_in[4];

    const int n_nodes = in_sizes[2] / 3;   // pos is [N,3]
    const int C       = in_sizes[4];       // sample_index is [C]

    float* out  = (float*)d_out;
    float* xp   = out;
    float* hp   = out + (size_t)C * DF;
    float* pout = out + (size_t)2 * C * DF;

    // workspace layout (ints): counts[C] | cursor[C] | offsets[C] | blocksums[256] | node_list[N]
    int* counts    = (int*)d_ws;
    int* cursor    = counts + C;
    int* offsets   = cursor + C;
    int* blocksums = offsets + C;
    int* node_list = blocksums + 256;

    // zero counts + cursor (contiguous) each call
    hipMemsetAsync(counts, 0, (size_t)2 * C * sizeof(int), stream);

    cp_count<<<(n_nodes + 255) / 256, 256, 0, stream>>>(cmap, counts, n_nodes);

    int nb = (C + 255) / 256;
    cp_scanA<<<nb, 256, 0, stream>>>(counts, offsets, blocksums, C);
    cp_scanB<<<1, 256, 0, stream>>>(blocksums, nb);
    cp_scanC<<<nb, 256, 0, stream>>>(offsets, blocksums, C);

    cp_fill<<<(n_nodes + 255) / 256, 256, 0, stream>>>(cmap, offsets, cursor, node_list, n_nodes);

    cp_pool<<<(C + 3) / 4, 256, 0, stream>>>(x, h, offsets, counts, node_list, xp, hp, C);

    cp_pos<<<(C + 255) / 256, 256, 0, stream>>>(pos, sidx, pout, C);
}

// Round 3
// 145.697 us; speedup vs baseline: 9.6295x; 1.0189x over previous
//
#include <hip/hip_runtime.h>

#define DF 256  // feature dim

// ---- 1. histogram ----
__global__ void cp_count(const int* __restrict__ cmap, int* __restrict__ counts, int n) {
    int i = blockIdx.x * blockDim.x + threadIdx.x;
    if (i < n) atomicAdd(&counts[cmap[i]], 1);
}

// ---- 2a. per-block exclusive scan ----
__global__ void cp_scanA(const int* __restrict__ counts, int* __restrict__ offsets,
                         int* __restrict__ blocksums, int C) {
    __shared__ int s[256];
    int tid = threadIdx.x;
    int i = blockIdx.x * 256 + tid;
    int v = (i < C) ? counts[i] : 0;
    s[tid] = v;
    __syncthreads();
    for (int off = 1; off < 256; off <<= 1) {
        int t = (tid >= off) ? s[tid - off] : 0;
        __syncthreads();
        s[tid] += t;
        __syncthreads();
    }
    if (i < C) offsets[i] = s[tid] - v;
    if (tid == 255) blocksums[blockIdx.x] = s[255];
}

// ---- 2b. scan block sums ----
__global__ void cp_scanB(int* __restrict__ blocksums, int nb) {
    __shared__ int s[256];
    int tid = threadIdx.x;
    if (nb <= 256) {
        int v = (tid < nb) ? blocksums[tid] : 0;
        s[tid] = v;
        __syncthreads();
        for (int off = 1; off < 256; off <<= 1) {
            int t = (tid >= off) ? s[tid - off] : 0;
            __syncthreads();
            s[tid] += t;
            __syncthreads();
        }
        if (tid < nb) blocksums[tid] = s[tid] - v;
    } else if (tid == 0) {
        int run = 0;
        for (int k = 0; k < nb; ++k) { int t = blocksums[k]; blocksums[k] = run; run += t; }
    }
}

// ---- 2c. add block offsets; also build fused seg[c] = {start, len} ----
__global__ void cp_scanC(int* __restrict__ offsets, const int* __restrict__ blocksums,
                         const int* __restrict__ counts, int2* __restrict__ seg, int C) {
    int i = blockIdx.x * 256 + threadIdx.x;
    if (i < C) {
        int st = offsets[i] + blocksums[blockIdx.x];
        offsets[i] = st;
        seg[i] = make_int2(st, counts[i]);
    }
}

// ---- 3. bucket-fill ----
__global__ void cp_fill(const int* __restrict__ cmap, const int* __restrict__ offsets,
                        int* __restrict__ cursor, int* __restrict__ node_list, int n) {
    int i = blockIdx.x * blockDim.x + threadIdx.x;
    if (i < n) {
        int c = cmap[i];
        int slot = atomicAdd(&cursor[c], 1);
        node_list[offsets[c] + slot] = i;
    }
}

// ---- 4. pool: one wave per cluster, prefetched indices + unrolled loads ----
__global__ void cp_pool(const float* __restrict__ x, const float* __restrict__ h,
                        const int2* __restrict__ seg, const int* __restrict__ node_list,
                        float* __restrict__ xp, float* __restrict__ hp, int C) {
    int c = blockIdx.x * 4 + (threadIdx.x >> 6);
    if (c >= C) return;
    int lane = threadIdx.x & 63;
    int2 sl = seg[c];                      // one 8B load: {start, len}
    int start = sl.x, len = sl.y;

    // preload up to 64 node ids in a single coalesced vector load
    int nid = 0;
    if (lane < len) nid = node_list[start + lane];

    float4 ax = make_float4(0.f, 0.f, 0.f, 0.f);
    float4 ah = make_float4(0.f, 0.f, 0.f, 0.f);
    int kmax = len < 64 ? len : 64;
    int k = 0;
    for (; k + 4 <= kmax; k += 4) {
        int n0 = __shfl(nid, k);
        int n1 = __shfl(nid, k + 1);
        int n2 = __shfl(nid, k + 2);
        int n3 = __shfl(nid, k + 3);
        float4 x0 = reinterpret_cast<const float4*>(x + (size_t)n0 * DF)[lane];
        float4 h0 = reinterpret_cast<const float4*>(h + (size_t)n0 * DF)[lane];
        float4 x1 = reinterpret_cast<const float4*>(x + (size_t)n1 * DF)[lane];
        float4 h1 = reinterpret_cast<const float4*>(h + (size_t)n1 * DF)[lane];
        float4 x2 = reinterpret_cast<const float4*>(x + (size_t)n2 * DF)[lane];
        float4 h2 = reinterpret_cast<const float4*>(h + (size_t)n2 * DF)[lane];
        float4 x3 = reinterpret_cast<const float4*>(x + (size_t)n3 * DF)[lane];
        float4 h3 = reinterpret_cast<const float4*>(h + (size_t)n3 * DF)[lane];
        ax.x += x0.x + x1.x + x2.x + x3.x;
        ax.y += x0.y + x1.y + x2.y + x3.y;
        ax.z += x0.z + x1.z + x2.z + x3.z;
        ax.w += x0.w + x1.w + x2.w + x3.w;
        ah.x += h0.x + h1.x + h2.x + h3.x;
        ah.y += h0.y + h1.y + h2.y + h3.y;
        ah.z += h0.z + h1.z + h2.z + h3.z;
        ah.w += h0.w + h1.w + h2.w + h3.w;
    }
    for (; k < kmax; ++k) {
        int n0 = __shfl(nid, k);
        float4 x0 = reinterpret_cast<const float4*>(x + (size_t)n0 * DF)[lane];
        float4 h0 = reinterpret_cast<const float4*>(h + (size_t)n0 * DF)[lane];
        ax.x += x0.x; ax.y += x0.y; ax.z += x0.z; ax.w += x0.w;
        ah.x += h0.x; ah.y += h0.y; ah.z += h0.z; ah.w += h0.w;
    }
    // rare tail (len > 64): serial fallback
    for (int kk = 64; kk < len; ++kk) {
        int n0 = node_list[start + kk];
        float4 x0 = reinterpret_cast<const float4*>(x + (size_t)n0 * DF)[lane];
        float4 h0 = reinterpret_cast<const float4*>(h + (size_t)n0 * DF)[lane];
        ax.x += x0.x; ax.y += x0.y; ax.z += x0.z; ax.w += x0.w;
        ah.x += h0.x; ah.y += h0.y; ah.z += h0.z; ah.w += h0.w;
    }

    float inv = 1.0f / (float)(len > 0 ? len : 1);
    ax.x *= inv; ax.y *= inv; ax.z *= inv; ax.w *= inv;
    ah.x *= inv; ah.y *= inv; ah.z *= inv; ah.w *= inv;
    reinterpret_cast<float4*>(xp + (size_t)c * DF)[lane] = ax;
    reinterpret_cast<float4*>(hp + (size_t)c * DF)[lane] = ah;
}

// ---- 5. pos gather ----
__global__ void cp_pos(const float* __restrict__ pos, const int* __restrict__ sidx,
                       float* __restrict__ out, int C) {
    int i = blockIdx.x * blockDim.x + threadIdx.x;
    if (i >= C) return;
    int s = sidx[i];
    out[(size_t)i * 3 + 0] = pos[(size_t)s * 3 + 0];
    out[(size_t)i * 3 + 1] = pos[(size_t)s * 3 + 1];
    out[(size_t)i * 3 + 2] = pos[(size_t)s * 3 + 2];
}

extern "C" void kernel_launch(void* const* d_in, const int* in_sizes, int n_in,
                              void* d_out, int out_size, void* d_ws, size_t ws_size,
                              hipStream_t stream) {
    const float* x    = (const float*)d_in[0];
    const float* h    = (const float*)d_in[1];
    const float* pos  = (const float*)d_in[2];
    const int*   cmap = (const int*)d_in[3];
    const int*   sidx = (const int*)d_in[4];

    const int n_nodes = in_sizes[2] / 3;
    const int C       = in_sizes[4];

    float* out  = (float*)d_out;
    float* xp   = out;
    float* hp   = out + (size_t)C * DF;
    float* pout = out + (size_t)2 * C * DF;

    // ws ints: counts[C] | cursor[C] | offsets[C] | blocksums[256] | seg[2C] | node_list[N]
    int*  counts    = (int*)d_ws;
    int*  cursor    = counts + C;
    int*  offsets   = cursor + C;
    int*  blocksums = offsets + C;
    int2* seg       = (int2*)(blocksums + 256);
    int*  node_list = (int*)(seg + C);

    hipMemsetAsync(counts, 0, (size_t)2 * C * sizeof(int), stream);

    cp_count<<<(n_nodes + 255) / 256, 256, 0, stream>>>(cmap, counts, n_nodes);

    int nb = (C + 255) / 256;
    cp_scanA<<<nb, 256, 0, stream>>>(counts, offsets, blocksums, C);
    cp_scanB<<<1, 256, 0, stream>>>(blocksums, nb);
    cp_scanC<<<nb, 256, 0, stream>>>(offsets, blocksums, counts, seg, C);

    cp_fill<<<(n_nodes + 255) / 256, 256, 0, stream>>>(cmap, offsets, cursor, node_list, n_nodes);

    cp_pool<<<(C + 3) / 4, 256, 0, stream>>>(x, h, seg, node_list, xp, hp, C);

    cp_pos<<<(C + 255) / 256, 256, 0, stream>>>(pos, sidx, pout, C);
}